// Round 1
// baseline (555.190 us; speedup 1.0000x reference)
//
#include <hip/hip_runtime.h>
#include <cstdint>
#include <cstddef>

// GAT layer forward for MI355X (gfx950).
// Shapes (derived at runtime from in_sizes): N=50000, E=1.6M, F=256, H=64.
// Outputs (concatenated in d_out): out [N,H] f32, alpha [E] f32.

constexpr int FDIM = 256;
constexpr int HDIM = 64;
constexpr float LEAKY = 0.05f;

// ---------------------------------------------------------------------------
// K1: z = x @ fc_w^T  (per-wave: 64 lanes = 64 output channels, 4 nodes/wave)
//     also s1[n] = z[n]·a_w[:64], s2[n] = z[n]·a_w[64:]
// fc_w staged in LDS padded to 260 floats/row -> conflict-free b128 reads.
// x rows staged per-wave in LDS; reads are same-address broadcasts (free).
// ---------------------------------------------------------------------------
__global__ __launch_bounds__(1024) void k_fc(
    const float* __restrict__ x, const float* __restrict__ fcw,
    const float* __restrict__ aw,
    float* __restrict__ z, float* __restrict__ s1, float* __restrict__ s2,
    int N, int nBlocks)
{
  __shared__ float fc_lds[HDIM * 260];          // 66.56 KB
  __shared__ float x_lds[16 * 4 * FDIM];        // 64 KB (16 waves * 4 rows)

  const int tid = threadIdx.x;
  // Stage fc_w: global coalesced, LDS write conflict-free (consecutive k).
  for (int i = tid; i < HDIM * FDIM; i += 1024) {
    int h = i >> 8;          // /256
    int k = i & 255;
    fc_lds[h * 260 + k] = fcw[i];
  }
  const int lane = tid & 63;
  const int wave = tid >> 6;
  const float aw1 = aw[lane];
  const float aw2 = aw[HDIM + lane];
  __syncthreads();

  const int iters = (N + nBlocks * 64 - 1) / (nBlocks * 64);
  const float* fcrow = &fc_lds[lane * 260];
  float* xstage = &x_lds[wave * 4 * FDIM];

  for (int it = 0; it < iters; ++it) {
    const int n0 = (blockIdx.x + it * nBlocks) * 64 + wave * 4;
    // stage up to 4 x-rows for this wave (full row coalesced: 64 lanes x 16B)
    #pragma unroll
    for (int m = 0; m < 4; ++m) {
      if (n0 + m < N) {
        const float4 v = *reinterpret_cast<const float4*>(
            x + (size_t)(n0 + m) * FDIM + lane * 4);
        *reinterpret_cast<float4*>(&xstage[m * FDIM + lane * 4]) = v;
      }
    }
    __syncthreads();   // uniform trip count across block: safe

    float acc0 = 0.f, acc1 = 0.f, acc2 = 0.f, acc3 = 0.f;
    #pragma unroll 4
    for (int k4 = 0; k4 < FDIM / 4; ++k4) {
      const float4 w  = *reinterpret_cast<const float4*>(fcrow + 4 * k4);
      const float4 x0 = *reinterpret_cast<const float4*>(xstage + 0 * FDIM + 4 * k4);
      const float4 x1 = *reinterpret_cast<const float4*>(xstage + 1 * FDIM + 4 * k4);
      const float4 x2 = *reinterpret_cast<const float4*>(xstage + 2 * FDIM + 4 * k4);
      const float4 x3 = *reinterpret_cast<const float4*>(xstage + 3 * FDIM + 4 * k4);
      acc0 = fmaf(w.x, x0.x, fmaf(w.y, x0.y, fmaf(w.z, x0.z, fmaf(w.w, x0.w, acc0))));
      acc1 = fmaf(w.x, x1.x, fmaf(w.y, x1.y, fmaf(w.z, x1.z, fmaf(w.w, x1.w, acc1))));
      acc2 = fmaf(w.x, x2.x, fmaf(w.y, x2.y, fmaf(w.z, x2.z, fmaf(w.w, x2.w, acc2))));
      acc3 = fmaf(w.x, x3.x, fmaf(w.y, x3.y, fmaf(w.z, x3.z, fmaf(w.w, x3.w, acc3))));
    }

    float accs[4] = {acc0, acc1, acc2, acc3};
    #pragma unroll
    for (int m = 0; m < 4; ++m) {
      const int n = n0 + m;
      if (n < N) {
        z[(size_t)n * HDIM + lane] = accs[m];
        float t1 = accs[m] * aw1;
        float t2 = accs[m] * aw2;
        #pragma unroll
        for (int off = 32; off > 0; off >>= 1) {
          t1 += __shfl_xor(t1, off, 64);
          t2 += __shfl_xor(t2, off, 64);
        }
        if (lane == 0) { s1[n] = t1; s2[n] = t2; }
      }
    }
    __syncthreads();   // WAR: next iteration overwrites x_lds
  }
}

// ---------------------------------------------------------------------------
// K2: per-edge attention numerator h_e = exp(leaky_relu(s1[src]+s2[dst]+b))
//     + segment sum into h_sum[src] via atomics (1.6M atomics on 50K cells).
// ---------------------------------------------------------------------------
__global__ __launch_bounds__(256) void k_edge_h(
    const int* __restrict__ src, const int* __restrict__ dst,
    const float* __restrict__ s1, const float* __restrict__ s2,
    const float* __restrict__ ab,
    float* __restrict__ hbuf, float* __restrict__ hsum, int E)
{
  int e = blockIdx.x * blockDim.x + threadIdx.x;
  if (e >= E) return;
  const int s = src[e];
  const int d = dst[e];
  float v = s1[s] + s2[d] + ab[0];
  v = v > 0.f ? v : LEAKY * v;
  const float h = __expf(v);
  hbuf[e] = h;
  atomicAdd(&hsum[s], h);
}

// ---------------------------------------------------------------------------
// K3: one wave per edge, lane = feature.
//     alpha_e = h_e / h_sum[src]; out[src][:] += alpha_e * z[dst][:]
// ---------------------------------------------------------------------------
__global__ __launch_bounds__(256) void k_edge_out(
    const int* __restrict__ src, const int* __restrict__ dst,
    const float* __restrict__ z, const float* __restrict__ hbuf,
    const float* __restrict__ hsum,
    float* __restrict__ out, float* __restrict__ alpha, int E)
{
  const long long gid = (long long)blockIdx.x * blockDim.x + threadIdx.x;
  const int e = (int)(gid >> 6);
  const int lane = threadIdx.x & 63;
  if (e >= E) return;
  const int s = src[e];
  const int d = dst[e];
  const float a = hbuf[e] / hsum[s];
  if (lane == 0) alpha[e] = a;
  const float zv = z[(size_t)d * HDIM + lane];
  atomicAdd(out + (size_t)s * HDIM + lane, a * zv);
}

extern "C" void kernel_launch(void* const* d_in, const int* in_sizes, int n_in,
                              void* d_out, int out_size, void* d_ws, size_t ws_size,
                              hipStream_t stream) {
  const int E  = in_sizes[1] / 2;
  const int H2 = in_sizes[3];            // 2*H = 128
  const int Hh = H2 / 2;                 // 64
  const int Ff = in_sizes[2] / Hh;       // 256
  const int N  = in_sizes[0] / Ff;       // 50000

  const float* x   = (const float*)d_in[0];
  const int*   ei  = (const int*)d_in[1];
  const float* fcw = (const float*)d_in[2];
  const float* aw  = (const float*)d_in[3];
  const float* ab  = (const float*)d_in[4];
  const int* src = ei;
  const int* dst = ei + E;

  float* out   = (float*)d_out;
  float* alpha = out + (size_t)N * HDIM;

  // workspace layout (floats): z [N*64] | s1 [N] | s2 [N] | hsum [N] | h [E]
  float* ws   = (float*)d_ws;
  float* z    = ws;
  float* s1   = z + (size_t)N * HDIM;
  float* s2   = s1 + N;
  float* hsum = s2 + N;
  float* hbuf = hsum + N;

  hipMemsetAsync(out,  0, (size_t)N * HDIM * sizeof(float), stream);
  hipMemsetAsync(hsum, 0, (size_t)N * sizeof(float), stream);

  const int nB = 256;
  k_fc<<<nB, 1024, 0, stream>>>(x, fcw, aw, z, s1, s2, N, nB);

  k_edge_h<<<(E + 255) / 256, 256, 0, stream>>>(src, dst, s1, s2, ab, hbuf, hsum, E);

  const long long tot = (long long)E * 64;
  k_edge_out<<<(int)((tot + 255) / 256), 256, 0, stream>>>(
      src, dst, z, hbuf, hsum, out, alpha, E);
}

// Round 2
// 498.989 us; speedup vs baseline: 1.1126x; 1.1126x over previous
//
#include <hip/hip_runtime.h>
#include <cstdint>
#include <cstddef>

// GAT layer forward for MI355X (gfx950).
// N=50000, E=1.6M, F=256, H=64 (derived at runtime).
// Outputs (concat in d_out): out [N,H] f32, alpha [E] f32.

constexpr int FDIM = 256;
constexpr int HDIM = 64;
constexpr float LEAKY = 0.05f;

// ---------------------------------------------------------------------------
// K1: z = x @ fc_w^T ; s1[n]=z[n]·a_w[:64] ; s2[n]=z[n]·a_w[64:]
// ---------------------------------------------------------------------------
__global__ __launch_bounds__(1024) void k_fc(
    const float* __restrict__ x, const float* __restrict__ fcw,
    const float* __restrict__ aw,
    float* __restrict__ z, float* __restrict__ s1, float* __restrict__ s2,
    int N, int nBlocks)
{
  __shared__ float fc_lds[HDIM * 260];          // 66.56 KB
  __shared__ float x_lds[16 * 4 * FDIM];        // 64 KB (16 waves * 4 rows)

  const int tid = threadIdx.x;
  for (int i = tid; i < HDIM * FDIM; i += 1024) {
    int h = i >> 8;
    int k = i & 255;
    fc_lds[h * 260 + k] = fcw[i];
  }
  const int lane = tid & 63;
  const int wave = tid >> 6;
  const float aw1 = aw[lane];
  const float aw2 = aw[HDIM + lane];
  __syncthreads();

  const int iters = (N + nBlocks * 64 - 1) / (nBlocks * 64);
  const float* fcrow = &fc_lds[lane * 260];
  float* xstage = &x_lds[wave * 4 * FDIM];

  for (int it = 0; it < iters; ++it) {
    const int n0 = (blockIdx.x + it * nBlocks) * 64 + wave * 4;
    #pragma unroll
    for (int m = 0; m < 4; ++m) {
      if (n0 + m < N) {
        const float4 v = *reinterpret_cast<const float4*>(
            x + (size_t)(n0 + m) * FDIM + lane * 4);
        *reinterpret_cast<float4*>(&xstage[m * FDIM + lane * 4]) = v;
      }
    }
    __syncthreads();

    float acc0 = 0.f, acc1 = 0.f, acc2 = 0.f, acc3 = 0.f;
    #pragma unroll 4
    for (int k4 = 0; k4 < FDIM / 4; ++k4) {
      const float4 w  = *reinterpret_cast<const float4*>(fcrow + 4 * k4);
      const float4 x0 = *reinterpret_cast<const float4*>(xstage + 0 * FDIM + 4 * k4);
      const float4 x1 = *reinterpret_cast<const float4*>(xstage + 1 * FDIM + 4 * k4);
      const float4 x2 = *reinterpret_cast<const float4*>(xstage + 2 * FDIM + 4 * k4);
      const float4 x3 = *reinterpret_cast<const float4*>(xstage + 3 * FDIM + 4 * k4);
      acc0 = fmaf(w.x, x0.x, fmaf(w.y, x0.y, fmaf(w.z, x0.z, fmaf(w.w, x0.w, acc0))));
      acc1 = fmaf(w.x, x1.x, fmaf(w.y, x1.y, fmaf(w.z, x1.z, fmaf(w.w, x1.w, acc1))));
      acc2 = fmaf(w.x, x2.x, fmaf(w.y, x2.y, fmaf(w.z, x2.z, fmaf(w.w, x2.w, acc2))));
      acc3 = fmaf(w.x, x3.x, fmaf(w.y, x3.y, fmaf(w.z, x3.z, fmaf(w.w, x3.w, acc3))));
    }

    float accs[4] = {acc0, acc1, acc2, acc3};
    #pragma unroll
    for (int m = 0; m < 4; ++m) {
      const int n = n0 + m;
      if (n < N) {
        z[(size_t)n * HDIM + lane] = accs[m];
        float t1 = accs[m] * aw1;
        float t2 = accs[m] * aw2;
        #pragma unroll
        for (int off = 32; off > 0; off >>= 1) {
          t1 += __shfl_xor(t1, off, 64);
          t2 += __shfl_xor(t2, off, 64);
        }
        if (lane == 0) { s1[n] = t1; s2[n] = t2; }
      }
    }
    __syncthreads();
  }
}

// ---------------------------------------------------------------------------
// K2: histogram of src
// ---------------------------------------------------------------------------
__global__ __launch_bounds__(256) void k_hist(
    const int* __restrict__ src, int* __restrict__ cnt, int E)
{
  int e = blockIdx.x * blockDim.x + threadIdx.x;
  if (e >= E) return;
  atomicAdd(&cnt[src[e]], 1);
}

// ---------------------------------------------------------------------------
// K3: single-block exclusive scan of cnt -> rowptr[N+1], cursor[N]
// ---------------------------------------------------------------------------
__global__ __launch_bounds__(1024) void k_scan(
    const int* __restrict__ cnt, int* __restrict__ rowptr,
    int* __restrict__ cursor, int N, int E)
{
  __shared__ int part[1024];
  const int tid = threadIdx.x;
  const int chunk = (N + 1023) >> 10;
  const int begin = min(tid * chunk, N);
  const int end = min(begin + chunk, N);
  int s = 0;
  for (int i = begin; i < end; ++i) s += cnt[i];
  part[tid] = s;
  __syncthreads();
  // inclusive scan (Hillis-Steele)
  for (int off = 1; off < 1024; off <<= 1) {
    int t = (tid >= off) ? part[tid - off] : 0;
    __syncthreads();
    part[tid] += t;
    __syncthreads();
  }
  int running = part[tid] - s;     // exclusive base for this chunk
  for (int i = begin; i < end; ++i) {
    rowptr[i] = running;
    cursor[i] = running;
    running += cnt[i];
  }
  if (tid == 0) rowptr[N] = E;
}

// ---------------------------------------------------------------------------
// K4: CSR scatter of dst (order within a node is arbitrary)
// ---------------------------------------------------------------------------
__global__ __launch_bounds__(256) void k_scatter(
    const int* __restrict__ src, const int* __restrict__ dst,
    int* __restrict__ cursor, int* __restrict__ csr_dst, int E)
{
  int e = blockIdx.x * blockDim.x + threadIdx.x;
  if (e >= E) return;
  int pos = atomicAdd(&cursor[src[e]], 1);
  csr_dst[pos] = dst[e];
}

// ---------------------------------------------------------------------------
// K5: node-centric accumulate. One wave per node, lane = feature.
// out[n] = (sum_e h_e * z[dst_e]) / (sum_e h_e);  hsum[n] = sum_e h_e
// ---------------------------------------------------------------------------
__global__ __launch_bounds__(256) void k_node(
    const int* __restrict__ csr_dst, const int* __restrict__ rowptr,
    const float* __restrict__ s1, const float* __restrict__ s2,
    const float* __restrict__ ab, const float* __restrict__ z,
    float* __restrict__ out, float* __restrict__ hsum, int N)
{
  const int node = blockIdx.x * 4 + (threadIdx.x >> 6);
  const int lane = threadIdx.x & 63;
  if (node >= N) return;
  const int r0 = rowptr[node];
  const int r1 = rowptr[node + 1];
  if (r1 == r0) {            // degree-0: reference yields zeros
    out[(size_t)node * HDIM + lane] = 0.f;
    if (lane == 0) hsum[node] = 0.f;
    return;
  }
  const float s1n = s1[node];
  const float b = ab[0];
  float acc = 0.f, hs = 0.f;

  for (int base = r0; base < r1; base += 64) {
    const int j = base + lane;
    float h = 0.f;
    int dl = 0;
    if (j < r1) {
      dl = csr_dst[j];                       // coalesced
      float v = s1n + s2[dl] + b;            // gathered 4B (L2-resident, 200KB)
      v = v > 0.f ? v : LEAKY * v;
      h = __expf(v);
    }
    hs += h;
    const int cnt = min(64, r1 - base);
    for (int t = 0; t < cnt; ++t) {
      const float ht = __shfl(h, t, 64);
      const int   dt = __shfl(dl, t, 64);
      acc = fmaf(ht, z[(size_t)dt * HDIM + lane], acc);   // coalesced 256B row
    }
  }
  #pragma unroll
  for (int off = 32; off > 0; off >>= 1) hs += __shfl_xor(hs, off, 64);
  out[(size_t)node * HDIM + lane] = acc / hs;
  if (lane == 0) hsum[node] = hs;
}

// ---------------------------------------------------------------------------
// K6: alpha in edge order (coalesced writes)
// ---------------------------------------------------------------------------
__global__ __launch_bounds__(256) void k_alpha(
    const int* __restrict__ src, const int* __restrict__ dst,
    const float* __restrict__ s1, const float* __restrict__ s2,
    const float* __restrict__ ab, const float* __restrict__ hsum,
    float* __restrict__ alpha, int E)
{
  int e = blockIdx.x * blockDim.x + threadIdx.x;
  if (e >= E) return;
  const int s = src[e];
  float v = s1[s] + s2[dst[e]] + ab[0];
  v = v > 0.f ? v : LEAKY * v;
  alpha[e] = __expf(v) / hsum[s];
}

extern "C" void kernel_launch(void* const* d_in, const int* in_sizes, int n_in,
                              void* d_out, int out_size, void* d_ws, size_t ws_size,
                              hipStream_t stream) {
  const int E  = in_sizes[1] / 2;
  const int H2 = in_sizes[3];            // 2*H = 128
  const int Hh = H2 / 2;                 // 64
  const int Ff = in_sizes[2] / Hh;       // 256
  const int N  = in_sizes[0] / Ff;       // 50000

  const float* x   = (const float*)d_in[0];
  const int*   ei  = (const int*)d_in[1];
  const float* fcw = (const float*)d_in[2];
  const float* aw  = (const float*)d_in[3];
  const float* ab  = (const float*)d_in[4];
  const int* src = ei;
  const int* dst = ei + E;

  float* out   = (float*)d_out;
  float* alpha = out + (size_t)N * HDIM;

  // workspace layout:
  // z [N*64] f32 | s1 [N] | s2 [N] | hsum [N] | cnt [N] i32 | rowptr [N+1] i32
  // | cursor [N] i32 | csr_dst [E] i32
  float* ws   = (float*)d_ws;
  float* z    = ws;
  float* s1   = z + (size_t)N * HDIM;
  float* s2   = s1 + N;
  float* hsum = s2 + N;
  int* cnt     = (int*)(hsum + N);
  int* rowptr  = cnt + N;
  int* cursor  = rowptr + (N + 1);
  int* csr_dst = cursor + N;

  hipMemsetAsync(cnt, 0, (size_t)N * sizeof(int), stream);

  const int nB = 256;
  k_fc<<<nB, 1024, 0, stream>>>(x, fcw, aw, z, s1, s2, N, nB);

  const int eb = (E + 255) / 256;
  k_hist<<<eb, 256, 0, stream>>>(src, cnt, E);
  k_scan<<<1, 1024, 0, stream>>>(cnt, rowptr, cursor, N, E);
  k_scatter<<<eb, 256, 0, stream>>>(src, dst, cursor, csr_dst, E);

  k_node<<<(N + 3) / 4, 256, 0, stream>>>(
      csr_dst, rowptr, s1, s2, ab, z, out, hsum, N);

  k_alpha<<<eb, 256, 0, stream>>>(src, dst, s1, s2, ab, hsum, alpha, E);
}

// Round 3
// 342.718 us; speedup vs baseline: 1.6200x; 1.4560x over previous
//
#include <hip/hip_runtime.h>
#include <cstdint>
#include <cstddef>

// GAT layer forward for MI355X (gfx950).
// N=50000, E=1.6M, F=256, H=64 (derived at runtime).
// Outputs (concat in d_out): out [N,H] f32, alpha [E] f32.

constexpr int FDIM = 256;
constexpr int HDIM = 64;
constexpr float LEAKY = 0.05f;
constexpr int XPAD = 257;   // odd stride: (lane*257+k)%32 = (lane+k)%32 -> 2-way (free)

// ---------------------------------------------------------------------------
// K0: wt[k][c] = fcw[c][k]  (64KB transpose so fc weights load as scalar rows)
// ---------------------------------------------------------------------------
__global__ __launch_bounds__(256) void k_wt(
    const float* __restrict__ fcw, float* __restrict__ wt)
{
  const int i = blockIdx.x * 256 + threadIdx.x;   // 0 .. 16383
  const int c = i >> 8;
  const int k = i & 255;
  wt[k * HDIM + c] = fcw[i];
}

// ---------------------------------------------------------------------------
// K1: z = x @ fc_w^T ; s1[n]=z[n]·a_w[:64] ; s2[n]=z[n]·a_w[64:]
// lane = node (64 nodes per block), wave = 8 output channels (8 waves).
// Weights via wave-uniform scalar loads (s_load) from wt; x via LDS b32
// reads at odd stride (conflict-free).
// ---------------------------------------------------------------------------
__global__ __launch_bounds__(512) void k_fc2(
    const float* __restrict__ x, const float* __restrict__ wt,
    const float* __restrict__ aw,
    float* __restrict__ z, float* __restrict__ s1, float* __restrict__ s2,
    int N)
{
  __shared__ float xl[64 * XPAD];        // 65.8 KB
  __shared__ float p1l[8 * 64];
  __shared__ float p2l[8 * 64];

  const int tid  = threadIdx.x;
  const int lane = tid & 63;
  const int wave = tid >> 6;
  const int n0   = blockIdx.x * 64;

  // Stage 64 x-rows. Per instr: lane -> consecutive k, bank = (r+lane+64j)%32
  // -> conflict-free LDS writes; global reads 256B-coalesced dwords.
  for (int r = wave; r < 64; r += 8) {
    const int n = n0 + r;
    if (n < N) {
      #pragma unroll
      for (int j = 0; j < 4; ++j)
        xl[r * XPAD + lane + 64 * j] = x[(size_t)n * FDIM + lane + 64 * j];
    }
  }
  __syncthreads();

  const int c0 = __builtin_amdgcn_readfirstlane(wave * 8);
  float acc[8] = {0, 0, 0, 0, 0, 0, 0, 0};
  const float* xrow = &xl[lane * XPAD];

  #pragma unroll 4
  for (int k = 0; k < FDIM; ++k) {
    const float xv = xrow[k];
    const float* wr = wt + (size_t)k * HDIM + c0;   // uniform -> s_load
    const float4 wa = *reinterpret_cast<const float4*>(wr);
    const float4 wb = *reinterpret_cast<const float4*>(wr + 4);
    acc[0] = fmaf(xv, wa.x, acc[0]);
    acc[1] = fmaf(xv, wa.y, acc[1]);
    acc[2] = fmaf(xv, wa.z, acc[2]);
    acc[3] = fmaf(xv, wa.w, acc[3]);
    acc[4] = fmaf(xv, wb.x, acc[4]);
    acc[5] = fmaf(xv, wb.y, acc[5]);
    acc[6] = fmaf(xv, wb.z, acc[6]);
    acc[7] = fmaf(xv, wb.w, acc[7]);
  }

  // partial dots for s1/s2 over this wave's 8 channels
  float p1 = 0.f, p2 = 0.f;
  #pragma unroll
  for (int j = 0; j < 8; ++j) {
    p1 = fmaf(acc[j], aw[c0 + j], p1);
    p2 = fmaf(acc[j], aw[HDIM + c0 + j], p2);
  }
  p1l[wave * 64 + lane] = p1;
  p2l[wave * 64 + lane] = p2;

  const int n = n0 + lane;
  if (n < N) {
    float4 a0 = {acc[0], acc[1], acc[2], acc[3]};
    float4 a1 = {acc[4], acc[5], acc[6], acc[7]};
    *reinterpret_cast<float4*>(z + (size_t)n * HDIM + c0)     = a0;
    *reinterpret_cast<float4*>(z + (size_t)n * HDIM + c0 + 4) = a1;
  }
  __syncthreads();
  if (wave == 0 && n < N) {
    float t1 = 0.f, t2 = 0.f;
    #pragma unroll
    for (int w = 0; w < 8; ++w) {
      t1 += p1l[w * 64 + lane];
      t2 += p2l[w * 64 + lane];
    }
    s1[n] = t1;
    s2[n] = t2;
  }
}

// ---------------------------------------------------------------------------
// K2: histogram of src, recording each edge's rank within its node.
// ---------------------------------------------------------------------------
__global__ __launch_bounds__(256) void k_hist(
    const int* __restrict__ src, int* __restrict__ cnt,
    unsigned short* __restrict__ rank, int E)
{
  int e = blockIdx.x * blockDim.x + threadIdx.x;
  if (e >= E) return;
  rank[e] = (unsigned short)atomicAdd(&cnt[src[e]], 1);
}

// ---------------------------------------------------------------------------
// K3: single-block exclusive scan of cnt -> rowptr[N+1]
// ---------------------------------------------------------------------------
__global__ __launch_bounds__(1024) void k_scan(
    const int* __restrict__ cnt, int* __restrict__ rowptr, int N, int E)
{
  __shared__ int part[1024];
  const int tid = threadIdx.x;
  const int chunk = (N + 1023) >> 10;
  const int begin = min(tid * chunk, N);
  const int end = min(begin + chunk, N);
  int s = 0;
  for (int i = begin; i < end; ++i) s += cnt[i];
  part[tid] = s;
  __syncthreads();
  for (int off = 1; off < 1024; off <<= 1) {
    int t = (tid >= off) ? part[tid - off] : 0;
    __syncthreads();
    part[tid] += t;
    __syncthreads();
  }
  int running = part[tid] - s;
  for (int i = begin; i < end; ++i) {
    rowptr[i] = running;
    running += cnt[i];
  }
  if (tid == 0) rowptr[N] = E;
}

// ---------------------------------------------------------------------------
// K4: atomic-free CSR placement: pos = rowptr[src] + rank
// ---------------------------------------------------------------------------
__global__ __launch_bounds__(256) void k_place(
    const int* __restrict__ src, const int* __restrict__ dst,
    const int* __restrict__ rowptr, const unsigned short* __restrict__ rank,
    int* __restrict__ csr_dst, int E)
{
  int e = blockIdx.x * blockDim.x + threadIdx.x;
  if (e >= E) return;
  csr_dst[rowptr[src[e]] + (int)rank[e]] = dst[e];
}

// ---------------------------------------------------------------------------
// K5: node-centric accumulate. One wave per node, lane = feature.
// out[n] = (sum_e h_e * z[dst_e]) / (sum_e h_e);  hsum[n] = sum_e h_e
// ---------------------------------------------------------------------------
__global__ __launch_bounds__(256) void k_node(
    const int* __restrict__ csr_dst, const int* __restrict__ rowptr,
    const float* __restrict__ s1, const float* __restrict__ s2,
    const float* __restrict__ ab, const float* __restrict__ z,
    float* __restrict__ out, float* __restrict__ hsum, int N)
{
  const int node = blockIdx.x * 4 + (threadIdx.x >> 6);
  const int lane = threadIdx.x & 63;
  if (node >= N) return;
  const int r0 = rowptr[node];
  const int r1 = rowptr[node + 1];
  if (r1 == r0) {            // degree-0: reference yields zeros
    out[(size_t)node * HDIM + lane] = 0.f;
    if (lane == 0) hsum[node] = 0.f;
    return;
  }
  const float s1n = s1[node];
  const float b = ab[0];
  float acc = 0.f, hs = 0.f;

  for (int base = r0; base < r1; base += 64) {
    const int j = base + lane;
    float h = 0.f;
    int dl = 0;
    if (j < r1) {
      dl = csr_dst[j];                       // coalesced
      float v = s1n + s2[dl] + b;            // gathered 4B (L2-resident)
      v = v > 0.f ? v : LEAKY * v;
      h = __expf(v);
    }
    hs += h;
    const int cnt = min(64, r1 - base);
    for (int t = 0; t < cnt; ++t) {
      const float ht = __shfl(h, t, 64);
      const int   dt = __shfl(dl, t, 64);
      acc = fmaf(ht, z[(size_t)dt * HDIM + lane], acc);   // coalesced 256B row
    }
  }
  #pragma unroll
  for (int off = 32; off > 0; off >>= 1) hs += __shfl_xor(hs, off, 64);
  out[(size_t)node * HDIM + lane] = acc / hs;
  if (lane == 0) hsum[node] = hs;
}

// ---------------------------------------------------------------------------
// K6: alpha in edge order (coalesced writes)
// ---------------------------------------------------------------------------
__global__ __launch_bounds__(256) void k_alpha(
    const int* __restrict__ src, const int* __restrict__ dst,
    const float* __restrict__ s1, const float* __restrict__ s2,
    const float* __restrict__ ab, const float* __restrict__ hsum,
    float* __restrict__ alpha, int E)
{
  int e = blockIdx.x * blockDim.x + threadIdx.x;
  if (e >= E) return;
  const int s = src[e];
  float v = s1[s] + s2[dst[e]] + ab[0];
  v = v > 0.f ? v : LEAKY * v;
  alpha[e] = __expf(v) / hsum[s];
}

extern "C" void kernel_launch(void* const* d_in, const int* in_sizes, int n_in,
                              void* d_out, int out_size, void* d_ws, size_t ws_size,
                              hipStream_t stream) {
  const int E  = in_sizes[1] / 2;
  const int H2 = in_sizes[3];            // 2*H = 128
  const int Hh = H2 / 2;                 // 64
  const int Ff = in_sizes[2] / Hh;       // 256
  const int N  = in_sizes[0] / Ff;       // 50000

  const float* x   = (const float*)d_in[0];
  const int*   ei  = (const int*)d_in[1];
  const float* fcw = (const float*)d_in[2];
  const float* aw  = (const float*)d_in[3];
  const float* ab  = (const float*)d_in[4];
  const int* src = ei;
  const int* dst = ei + E;

  float* out   = (float*)d_out;
  float* alpha = out + (size_t)N * HDIM;

  // workspace layout:
  // z [N*64] f32 | s1 [N] | s2 [N] | hsum [N] | wt [256*64] f32
  // | cnt [N] i32 | rowptr [N+1] i32 | csr_dst [E] i32 | rank [E] u16
  float* ws   = (float*)d_ws;
  float* z    = ws;
  float* s1   = z + (size_t)N * HDIM;
  float* s2   = s1 + N;
  float* hsum = s2 + N;
  float* wt   = hsum + N;
  int* cnt     = (int*)(wt + FDIM * HDIM);
  int* rowptr  = cnt + N;
  int* csr_dst = rowptr + (N + 1);
  unsigned short* rank = (unsigned short*)(csr_dst + E);

  hipMemsetAsync(cnt, 0, (size_t)N * sizeof(int), stream);

  k_wt<<<(FDIM * HDIM) / 256, 256, 0, stream>>>(fcw, wt);
  k_fc2<<<(N + 63) / 64, 512, 0, stream>>>(x, wt, aw, z, s1, s2, N);

  const int eb = (E + 255) / 256;
  k_hist<<<eb, 256, 0, stream>>>(src, cnt, rank, E);
  k_scan<<<1, 1024, 0, stream>>>(cnt, rowptr, N, E);
  k_place<<<eb, 256, 0, stream>>>(src, dst, rowptr, rank, csr_dst, E);

  k_node<<<(N + 3) / 4, 256, 0, stream>>>(
      csr_dst, rowptr, s1, s2, ab, z, out, hsum, N);

  k_alpha<<<eb, 256, 0, stream>>>(src, dst, s1, s2, ab, hsum, alpha, E);
}

// Round 5
// 271.498 us; speedup vs baseline: 2.0449x; 1.2623x over previous
//
#include <hip/hip_runtime.h>
#include <hip/hip_bf16.h>
#include <cstdint>
#include <cstddef>

// GAT layer forward for MI355X (gfx950).
// N=50000, E=1.6M, F=256, H=64 (derived at runtime).
// Outputs (concat in d_out): out [N,H] f32, alpha [E] f32.

constexpr int FDIM = 256;
constexpr int HDIM = 64;
constexpr float LEAKY = 0.05f;

typedef __attribute__((ext_vector_type(8))) short short8v;   // 8 bf16 = 4 VGPR
typedef __attribute__((ext_vector_type(4))) float f32x4;

__device__ __forceinline__ short bfs(float f) {
  return (short)__builtin_bit_cast(unsigned short, __float2bfloat16(f));
}
__device__ __forceinline__ short8v cvt8(float4 lo, float4 hi) {
  short8v r;
  r[0] = bfs(lo.x); r[1] = bfs(lo.y); r[2] = bfs(lo.z); r[3] = bfs(lo.w);
  r[4] = bfs(hi.x); r[5] = bfs(hi.y); r[6] = bfs(hi.z); r[7] = bfs(hi.w);
  return r;
}

// ---------------------------------------------------------------------------
// K0: pack fc_w (f32 [64][256]) into bf16 MFMA B-fragments.
// frag f = ks*4 + cb; lane l holds B[k = ks*32 + (l>>4)*8 + j][col = cb*16 +
// (l&15)] = fcw[col][k], j=0..7 contiguous: wb[(f*64 + l)*8 + j].
// A uses the same (l>>4, j) -> k map, so the shared k-permutation cancels.
// ---------------------------------------------------------------------------
__global__ __launch_bounds__(256) void k_wt(
    const float* __restrict__ fcw, short* __restrict__ wb)
{
  const int t = blockIdx.x * 256 + threadIdx.x;   // 0 .. 2047
  const int f = t >> 6;
  const int lane = t & 63;
  const int ks = f >> 2, cb = f & 3;
  const int col = cb * 16 + (lane & 15);
  const int kb = ks * 32 + (lane >> 4) * 8;
  short8v v;
  #pragma unroll
  for (int j = 0; j < 8; ++j) v[j] = bfs(fcw[col * FDIM + kb + j]);
  reinterpret_cast<short8v*>(wb)[t] = v;
}

// ---------------------------------------------------------------------------
// K1: MFMA GEMM z = x @ fc_w^T (bf16 in, f32 acc), fused s1/s2, z out bf16.
// Block: 256 thr = 4 waves, 128 rows. Per wave: 32 rows = 2 m-blocks x 4
// col-blocks of 16x16x32 MFMA over 8 k-steps.
// C/D layout (verified): col = lane&15, row = (lane>>4)*4 + reg.
// ---------------------------------------------------------------------------
__global__ __launch_bounds__(256) void k_fcm(
    const float* __restrict__ x, const short* __restrict__ wb,
    const float* __restrict__ aw,
    unsigned short* __restrict__ zb, float* __restrict__ s1,
    float* __restrict__ s2, int N)
{
  __shared__ __align__(16) unsigned short zt[128 * 72];   // 18.4 KB transpose buf

  const int tid = threadIdx.x;
  const int lane = tid & 63;
  const int wave = tid >> 6;
  const int n0 = blockIdx.x * 128;
  const int rb = n0 + wave * 32;
  const int l4 = lane >> 4;      // k-group / row-group
  const int lm = lane & 15;      // A-row / B-col within tile

  f32x4 acc[2][4] = {};

  const int r0c = min(rb + lm, N - 1);
  const int r1c = min(rb + 16 + lm, N - 1);
  const float* xp0 = x + (size_t)r0c * FDIM + l4 * 8;
  const float* xp1 = x + (size_t)r1c * FDIM + l4 * 8;
  const short8v* wbv = reinterpret_cast<const short8v*>(wb);

  #pragma unroll
  for (int ks = 0; ks < 8; ++ks) {
    const float4 a0l = *reinterpret_cast<const float4*>(xp0 + ks * 32);
    const float4 a0h = *reinterpret_cast<const float4*>(xp0 + ks * 32 + 4);
    const float4 a1l = *reinterpret_cast<const float4*>(xp1 + ks * 32);
    const float4 a1h = *reinterpret_cast<const float4*>(xp1 + ks * 32 + 4);
    const short8v fa0 = cvt8(a0l, a0h);
    const short8v fa1 = cvt8(a1l, a1h);
    #pragma unroll
    for (int cb = 0; cb < 4; ++cb) {
      const short8v fb = wbv[(ks * 4 + cb) * 64 + lane];
      acc[0][cb] = __builtin_amdgcn_mfma_f32_16x16x32_bf16(fa0, fb, acc[0][cb], 0, 0, 0);
      acc[1][cb] = __builtin_amdgcn_mfma_f32_16x16x32_bf16(fa1, fb, acc[1][cb], 0, 0, 0);
    }
  }

  // fused s1/s2: per row, dot over 64 cols with aw / aw+64
  float aw1l[4], aw2l[4];
  #pragma unroll
  for (int cb = 0; cb < 4; ++cb) {
    aw1l[cb] = aw[cb * 16 + lm];
    aw2l[cb] = aw[HDIM + cb * 16 + lm];
  }
  #pragma unroll
  for (int mb = 0; mb < 2; ++mb) {
    const int rloc = rb + mb * 16 + l4 * 4;
    #pragma unroll
    for (int reg = 0; reg < 4; ++reg) {
      float t1 = 0.f, t2 = 0.f;
      #pragma unroll
      for (int cb = 0; cb < 4; ++cb) {
        t1 = fmaf(acc[mb][cb][reg], aw1l[cb], t1);
        t2 = fmaf(acc[mb][cb][reg], aw2l[cb], t2);
      }
      #pragma unroll
      for (int off = 1; off < 16; off <<= 1) {
        t1 += __shfl_xor(t1, off, 64);
        t2 += __shfl_xor(t2, off, 64);
      }
      if (lm == reg && rloc + reg < N) {
        s1[rloc + reg] = t1;
        s2[rloc + reg] = t2;
      }
    }
  }

  // z -> bf16 via LDS transpose, then coalesced stores (64B per thread)
  #pragma unroll
  for (int mb = 0; mb < 2; ++mb)
    #pragma unroll
    for (int cb = 0; cb < 4; ++cb)
      #pragma unroll
      for (int reg = 0; reg < 4; ++reg) {
        const int rl = wave * 32 + mb * 16 + l4 * 4 + reg;
        zt[rl * 72 + cb * 16 + lm] =
            (unsigned short)__builtin_bit_cast(unsigned short,
                __float2bfloat16(acc[mb][cb][reg]));
      }
  __syncthreads();
  const int row = tid >> 1, hf = tid & 1;   // 32 u16 = 64 B = 4 x uint4 each
  const int n = n0 + row;
  if (n < N) {
    const uint4* s = reinterpret_cast<const uint4*>(&zt[row * 72 + hf * 32]);
    uint4 v0 = s[0], v1 = s[1], v2 = s[2], v3 = s[3];
    uint4* d = reinterpret_cast<uint4*>(zb + (size_t)n * HDIM + hf * 32);
    d[0] = v0; d[1] = v1; d[2] = v2; d[3] = v3;
  }
}

// ---------------------------------------------------------------------------
// K2: histogram of src, recording each edge's rank within its node.
// ---------------------------------------------------------------------------
__global__ __launch_bounds__(256) void k_hist(
    const int* __restrict__ src, int* __restrict__ cnt,
    unsigned short* __restrict__ rank, int E)
{
  int e = blockIdx.x * blockDim.x + threadIdx.x;
  if (e >= E) return;
  rank[e] = (unsigned short)atomicAdd(&cnt[src[e]], 1);
}

// ---------------------------------------------------------------------------
// K3: single-block exclusive scan of cnt -> rowptr[N+1]
// ---------------------------------------------------------------------------
__global__ __launch_bounds__(1024) void k_scan(
    const int* __restrict__ cnt, int* __restrict__ rowptr, int N, int E)
{
  __shared__ int part[1024];
  const int tid = threadIdx.x;
  const int chunk = (N + 1023) >> 10;
  const int begin = min(tid * chunk, N);
  const int end = min(begin + chunk, N);
  int s = 0;
  for (int i = begin; i < end; ++i) s += cnt[i];
  part[tid] = s;
  __syncthreads();
  for (int off = 1; off < 1024; off <<= 1) {
    int t = (tid >= off) ? part[tid - off] : 0;
    __syncthreads();
    part[tid] += t;
    __syncthreads();
  }
  int running = part[tid] - s;
  for (int i = begin; i < end; ++i) {
    rowptr[i] = running;
    running += cnt[i];
  }
  if (tid == 0) rowptr[N] = E;
}

// ---------------------------------------------------------------------------
// K4: atomic-free CSR placement (dst fits u16 since N < 65536)
// ---------------------------------------------------------------------------
__global__ __launch_bounds__(256) void k_place(
    const int* __restrict__ src, const int* __restrict__ dst,
    const int* __restrict__ rowptr, const unsigned short* __restrict__ rank,
    unsigned short* __restrict__ csr_dst, int E)
{
  int e = blockIdx.x * blockDim.x + threadIdx.x;
  if (e >= E) return;
  csr_dst[rowptr[src[e]] + (int)rank[e]] = (unsigned short)dst[e];
}

// ---------------------------------------------------------------------------
// K5: node-centric accumulate; wave/node; 2 edges per iteration.
// Lanes 0-31 handle even-indexed edges, 32-63 odd; each lane covers feature
// pair (2*(lane&31), +1) via one u32 (2 x bf16) gather.
// ---------------------------------------------------------------------------
__global__ __launch_bounds__(256) void k_node(
    const unsigned short* __restrict__ csr_dst, const int* __restrict__ rowptr,
    const float* __restrict__ s1, const float* __restrict__ s2,
    const float* __restrict__ ab, const unsigned short* __restrict__ zb,
    float* __restrict__ out, float* __restrict__ rinv, int N)
{
  const int node = blockIdx.x * 4 + (threadIdx.x >> 6);
  const int lane = threadIdx.x & 63;
  if (node >= N) return;
  const int r0 = rowptr[node];
  const int r1 = rowptr[node + 1];
  if (r1 == r0) {            // degree-0: reference yields zeros
    out[(size_t)node * HDIM + lane] = 0.f;
    if (lane == 0) rinv[node] = 0.f;
    return;
  }
  const float s1n = s1[node];
  const float b = ab[0];
  const int half = lane >> 5;
  const int fp = (lane & 31) << 1;   // feature pair base
  float ax = 0.f, ay = 0.f, hs = 0.f;

  for (int base = r0; base < r1; base += 64) {
    const int j = base + lane;
    float h = 0.f;
    int dl = 0;
    if (j < r1) {
      dl = (int)csr_dst[j];                  // coalesced u16
      float v = s1n + s2[dl] + b;            // gathered 4B (L2-resident)
      v = v > 0.f ? v : LEAKY * v;
      h = __expf(v);
    }
    hs += h;
    const int cnt = min(64, r1 - base);
    const int pairs = (cnt + 1) >> 1;
    for (int t = 0; t < pairs; ++t) {
      const int sl = 2 * t + half;           // lanes beyond cnt carry h=0
      const float hB = __shfl(h, sl, 64);
      const int dB = __shfl(dl, sl, 64);
      const unsigned int w = *reinterpret_cast<const unsigned int*>(
          zb + (size_t)dB * HDIM + fp);
      const float z0 = __uint_as_float(w << 16);
      const float z1 = __uint_as_float(w & 0xffff0000u);
      ax = fmaf(hB, z0, ax);
      ay = fmaf(hB, z1, ay);
    }
  }
  #pragma unroll
  for (int off = 32; off > 0; off >>= 1) hs += __shfl_xor(hs, off, 64);
  // combine even/odd halves (same feature pair lives at lane^32)
  ax += __shfl_xor(ax, 32, 64);
  ay += __shfl_xor(ay, 32, 64);
  const float inv = 1.0f / hs;
  if (lane < 32) {
    float2 o = {ax * inv, ay * inv};
    *reinterpret_cast<float2*>(out + (size_t)node * HDIM + fp) = o;
    if (lane == 0) rinv[node] = inv;
  }
}

// ---------------------------------------------------------------------------
// K6: alpha in edge order (coalesced writes)
// ---------------------------------------------------------------------------
__global__ __launch_bounds__(256) void k_alpha(
    const int* __restrict__ src, const int* __restrict__ dst,
    const float* __restrict__ s1, const float* __restrict__ s2,
    const float* __restrict__ ab, const float* __restrict__ rinv,
    float* __restrict__ alpha, int E)
{
  int e = blockIdx.x * blockDim.x + threadIdx.x;
  if (e >= E) return;
  const int s = src[e];
  float v = s1[s] + s2[dst[e]] + ab[0];
  v = v > 0.f ? v : LEAKY * v;
  alpha[e] = __expf(v) * rinv[s];
}

extern "C" void kernel_launch(void* const* d_in, const int* in_sizes, int n_in,
                              void* d_out, int out_size, void* d_ws, size_t ws_size,
                              hipStream_t stream) {
  const int E  = in_sizes[1] / 2;
  const int H2 = in_sizes[3];            // 2*H = 128
  const int Hh = H2 / 2;                 // 64
  const int Ff = in_sizes[2] / Hh;       // 256
  const int N  = in_sizes[0] / Ff;       // 50000

  const float* x   = (const float*)d_in[0];
  const int*   ei  = (const int*)d_in[1];
  const float* fcw = (const float*)d_in[2];
  const float* aw  = (const float*)d_in[3];
  const float* ab  = (const float*)d_in[4];
  const int* src = ei;
  const int* dst = ei + E;

  float* out   = (float*)d_out;
  float* alpha = out + (size_t)N * HDIM;

  // workspace layout:
  // zb u16[N*64] | s1 f32[N] | s2 f32[N] | rinv f32[N] | wb s16[16384]
  // | cnt i32[N] | rowptr i32[N+1] | rank u16[E] | csr_dst u16[E]
  unsigned short* zb = (unsigned short*)d_ws;
  float* s1   = (float*)(zb + (size_t)N * HDIM);
  float* s2   = s1 + N;
  float* rinv = s2 + N;
  short* wb   = (short*)(rinv + N);
  int* cnt    = (int*)(wb + 8 * 4 * 64 * 8);
  int* rowptr = cnt + N;
  unsigned short* rank    = (unsigned short*)(rowptr + (N + 1));
  unsigned short* csr_dst = rank + E;

  hipMemsetAsync(cnt, 0, (size_t)N * sizeof(int), stream);

  k_wt<<<8, 256, 0, stream>>>(fcw, wb);
  k_fcm<<<(N + 127) / 128, 256, 0, stream>>>(x, wb, aw, zb, s1, s2, N);

  const int eb = (E + 255) / 256;
  k_hist<<<eb, 256, 0, stream>>>(src, cnt, rank, E);
  k_scan<<<1, 1024, 0, stream>>>(cnt, rowptr, N, E);
  k_place<<<eb, 256, 0, stream>>>(src, dst, rowptr, rank, csr_dst, E);

  k_node<<<(N + 3) / 4, 256, 0, stream>>>(
      csr_dst, rowptr, s1, s2, ab, zb, out, rinv, N);

  k_alpha<<<eb, 256, 0, stream>>>(src, dst, s1, s2, ab, rinv, alpha, E);
}

// Round 6
// 203.560 us; speedup vs baseline: 2.7274x; 1.3337x over previous
//
#include <hip/hip_runtime.h>
#include <hip/hip_bf16.h>
#include <cstdint>
#include <cstddef>

// GAT layer forward for MI355X (gfx950).
// N=50000, E=1.6M, F=256, H=64 (derived at runtime).
// Outputs (concat in d_out): out [N,H] f32, alpha [E] f32.

constexpr int FDIM = 256;
constexpr int HDIM = 64;
constexpr float LEAKY = 0.05f;

typedef __attribute__((ext_vector_type(8))) short short8v;   // 8 bf16 = 4 VGPR
typedef __attribute__((ext_vector_type(4))) float f32x4;

__device__ __forceinline__ short bfs(float f) {
  return (short)__builtin_bit_cast(unsigned short, __float2bfloat16(f));
}
__device__ __forceinline__ short8v cvt8(float4 lo, float4 hi) {
  short8v r;
  r[0] = bfs(lo.x); r[1] = bfs(lo.y); r[2] = bfs(lo.z); r[3] = bfs(lo.w);
  r[4] = bfs(hi.x); r[5] = bfs(hi.y); r[6] = bfs(hi.z); r[7] = bfs(hi.w);
  return r;
}

// ---------------------------------------------------------------------------
// K0: pack fc_w (f32 [64][256]) into bf16 MFMA B-fragments.
// frag f = ks*4 + cb; lane l holds B[k = ks*32 + (l>>4)*8 + j][col = cb*16 +
// (l&15)] = fcw[col][k], j=0..7 contiguous: wb[(f*64 + l)*8 + j].
// A uses the same (l>>4, j) -> k map, so the shared k-permutation cancels.
// ---------------------------------------------------------------------------
__global__ __launch_bounds__(256) void k_wt(
    const float* __restrict__ fcw, short* __restrict__ wb)
{
  const int t = blockIdx.x * 256 + threadIdx.x;   // 0 .. 2047
  const int f = t >> 6;
  const int lane = t & 63;
  const int ks = f >> 2, cb = f & 3;
  const int col = cb * 16 + (lane & 15);
  const int kb = ks * 32 + (lane >> 4) * 8;
  short8v v;
  #pragma unroll
  for (int j = 0; j < 8; ++j) v[j] = bfs(fcw[col * FDIM + kb + j]);
  reinterpret_cast<short8v*>(wb)[t] = v;
}

// ---------------------------------------------------------------------------
// K1: MFMA GEMM z = x @ fc_w^T (bf16 in, f32 acc), fused s1/s2, z out bf16.
// Block: 256 thr = 4 waves, 128 rows. Per wave: 32 rows = 2 m-blocks x 4
// col-blocks of 16x16x32 MFMA over 8 k-steps.
// C/D layout (verified): col = lane&15, row = (lane>>4)*4 + reg.
// ---------------------------------------------------------------------------
__global__ __launch_bounds__(256) void k_fcm(
    const float* __restrict__ x, const short* __restrict__ wb,
    const float* __restrict__ aw,
    unsigned short* __restrict__ zb, float* __restrict__ s1,
    float* __restrict__ s2, int N)
{
  __shared__ __align__(16) unsigned short zt[128 * 72];   // 18.4 KB transpose buf

  const int tid = threadIdx.x;
  const int lane = tid & 63;
  const int wave = tid >> 6;
  const int n0 = blockIdx.x * 128;
  const int rb = n0 + wave * 32;
  const int l4 = lane >> 4;      // k-group / row-group
  const int lm = lane & 15;      // A-row / B-col within tile

  f32x4 acc[2][4] = {};

  const int r0c = min(rb + lm, N - 1);
  const int r1c = min(rb + 16 + lm, N - 1);
  const float* xp0 = x + (size_t)r0c * FDIM + l4 * 8;
  const float* xp1 = x + (size_t)r1c * FDIM + l4 * 8;
  const short8v* wbv = reinterpret_cast<const short8v*>(wb);

  #pragma unroll
  for (int ks = 0; ks < 8; ++ks) {
    const float4 a0l = *reinterpret_cast<const float4*>(xp0 + ks * 32);
    const float4 a0h = *reinterpret_cast<const float4*>(xp0 + ks * 32 + 4);
    const float4 a1l = *reinterpret_cast<const float4*>(xp1 + ks * 32);
    const float4 a1h = *reinterpret_cast<const float4*>(xp1 + ks * 32 + 4);
    const short8v fa0 = cvt8(a0l, a0h);
    const short8v fa1 = cvt8(a1l, a1h);
    #pragma unroll
    for (int cb = 0; cb < 4; ++cb) {
      const short8v fb = wbv[(ks * 4 + cb) * 64 + lane];
      acc[0][cb] = __builtin_amdgcn_mfma_f32_16x16x32_bf16(fa0, fb, acc[0][cb], 0, 0, 0);
      acc[1][cb] = __builtin_amdgcn_mfma_f32_16x16x32_bf16(fa1, fb, acc[1][cb], 0, 0, 0);
    }
  }

  // fused s1/s2: per row, dot over 64 cols with aw / aw+64
  float aw1l[4], aw2l[4];
  #pragma unroll
  for (int cb = 0; cb < 4; ++cb) {
    aw1l[cb] = aw[cb * 16 + lm];
    aw2l[cb] = aw[HDIM + cb * 16 + lm];
  }
  #pragma unroll
  for (int mb = 0; mb < 2; ++mb) {
    const int rloc = rb + mb * 16 + l4 * 4;
    #pragma unroll
    for (int reg = 0; reg < 4; ++reg) {
      float t1 = 0.f, t2 = 0.f;
      #pragma unroll
      for (int cb = 0; cb < 4; ++cb) {
        t1 = fmaf(acc[mb][cb][reg], aw1l[cb], t1);
        t2 = fmaf(acc[mb][cb][reg], aw2l[cb], t2);
      }
      #pragma unroll
      for (int off = 1; off < 16; off <<= 1) {
        t1 += __shfl_xor(t1, off, 64);
        t2 += __shfl_xor(t2, off, 64);
      }
      if (lm == reg && rloc + reg < N) {
        s1[rloc + reg] = t1;
        s2[rloc + reg] = t2;
      }
    }
  }

  // z -> bf16 via LDS transpose, then coalesced stores (64B per thread)
  #pragma unroll
  for (int mb = 0; mb < 2; ++mb)
    #pragma unroll
    for (int cb = 0; cb < 4; ++cb)
      #pragma unroll
      for (int reg = 0; reg < 4; ++reg) {
        const int rl = wave * 32 + mb * 16 + l4 * 4 + reg;
        zt[rl * 72 + cb * 16 + lm] =
            (unsigned short)__builtin_bit_cast(unsigned short,
                __float2bfloat16(acc[mb][cb][reg]));
      }
  __syncthreads();
  const int row = tid >> 1, hf = tid & 1;   // 32 u16 = 64 B = 4 x uint4 each
  const int n = n0 + row;
  if (n < N) {
    const uint4* s = reinterpret_cast<const uint4*>(&zt[row * 72 + hf * 32]);
    uint4 v0 = s[0], v1 = s[1], v2 = s[2], v3 = s[3];
    uint4* d = reinterpret_cast<uint4*>(zb + (size_t)n * HDIM + hf * 32);
    d[0] = v0; d[1] = v1; d[2] = v2; d[3] = v3;
  }
}

// ---------------------------------------------------------------------------
// K2: histogram of src, recording each edge's rank within its node.
// ---------------------------------------------------------------------------
__global__ __launch_bounds__(256) void k_hist(
    const int* __restrict__ src, int* __restrict__ cnt,
    unsigned short* __restrict__ rank, int E)
{
  int e = blockIdx.x * blockDim.x + threadIdx.x;
  if (e >= E) return;
  rank[e] = (unsigned short)atomicAdd(&cnt[src[e]], 1);
}

// ---------------------------------------------------------------------------
// K3a: per-block exclusive scan (1024/block) + block sums
// ---------------------------------------------------------------------------
__global__ __launch_bounds__(1024) void k_scan1(
    const int* __restrict__ cnt, int* __restrict__ rowptr,
    int* __restrict__ bsum, int N)
{
  __shared__ int wsum[16];
  const int i = blockIdx.x * 1024 + threadIdx.x;
  const int lane = threadIdx.x & 63;
  const int wave = threadIdx.x >> 6;
  const int v = (i < N) ? cnt[i] : 0;
  int s = v;
  #pragma unroll
  for (int off = 1; off < 64; off <<= 1) {
    int t = __shfl_up(s, off, 64);
    if (lane >= off) s += t;
  }
  if (lane == 63) wsum[wave] = s;
  __syncthreads();
  if (threadIdx.x < 16) {
    int w = wsum[threadIdx.x];
    #pragma unroll
    for (int off = 1; off < 16; off <<= 1) {
      int t = __shfl_up(w, off, 64);
      if (threadIdx.x >= off) w += t;
    }
    wsum[threadIdx.x] = w;   // inclusive across waves
  }
  __syncthreads();
  const int base = (wave > 0) ? wsum[wave - 1] : 0;
  if (i < N) rowptr[i] = base + s - v;      // block-local exclusive
  if (threadIdx.x == 0) bsum[blockIdx.x] = wsum[15];
}

// ---------------------------------------------------------------------------
// K3b: single-block exclusive scan of block sums (B <= 1024)
// ---------------------------------------------------------------------------
__global__ __launch_bounds__(1024) void k_scan2(int* __restrict__ bsum, int B)
{
  __shared__ int part[1024];
  const int t = threadIdx.x;
  const int v = (t < B) ? bsum[t] : 0;
  part[t] = v;
  __syncthreads();
  for (int off = 1; off < 1024; off <<= 1) {
    int u = (t >= off) ? part[t - off] : 0;
    __syncthreads();
    part[t] += u;
    __syncthreads();
  }
  if (t < B) bsum[t] = part[t] - v;   // exclusive
}

// ---------------------------------------------------------------------------
// K3c: add block offsets; set rowptr[N] = E
// ---------------------------------------------------------------------------
__global__ __launch_bounds__(1024) void k_scan3(
    int* __restrict__ rowptr, const int* __restrict__ bsum, int N, int E)
{
  const int i = blockIdx.x * 1024 + threadIdx.x;
  if (i < N) rowptr[i] += bsum[blockIdx.x];
  if (i == 0) rowptr[N] = E;
}

// ---------------------------------------------------------------------------
// K4: atomic-free CSR placement (dst fits u16 since N < 65536)
// ---------------------------------------------------------------------------
__global__ __launch_bounds__(256) void k_place(
    const int* __restrict__ src, const int* __restrict__ dst,
    const int* __restrict__ rowptr, const unsigned short* __restrict__ rank,
    unsigned short* __restrict__ csr_dst, int E)
{
  int e = blockIdx.x * blockDim.x + threadIdx.x;
  if (e >= E) return;
  csr_dst[rowptr[src[e]] + (int)rank[e]] = (unsigned short)dst[e];
}

// ---------------------------------------------------------------------------
// K5: node-centric accumulate; wave/node; 2 edges per iteration.
// Lanes 0-31 handle even-indexed edges, 32-63 odd; each lane covers feature
// pair (2*(lane&31), +1) via one u32 (2 x bf16) gather.
// ---------------------------------------------------------------------------
__global__ __launch_bounds__(256) void k_node(
    const unsigned short* __restrict__ csr_dst, const int* __restrict__ rowptr,
    const float* __restrict__ s1, const float* __restrict__ s2,
    const float* __restrict__ ab, const unsigned short* __restrict__ zb,
    float* __restrict__ out, float* __restrict__ rinv, int N)
{
  const int node = blockIdx.x * 4 + (threadIdx.x >> 6);
  const int lane = threadIdx.x & 63;
  if (node >= N) return;
  const int r0 = rowptr[node];
  const int r1 = rowptr[node + 1];
  if (r1 == r0) {            // degree-0: reference yields zeros
    out[(size_t)node * HDIM + lane] = 0.f;
    if (lane == 0) rinv[node] = 0.f;
    return;
  }
  const float s1n = s1[node];
  const float b = ab[0];
  const int half = lane >> 5;
  const int fp = (lane & 31) << 1;   // feature pair base
  float ax = 0.f, ay = 0.f, hs = 0.f;

  for (int base = r0; base < r1; base += 64) {
    const int j = base + lane;
    float h = 0.f;
    int dl = 0;
    if (j < r1) {
      dl = (int)csr_dst[j];                  // coalesced u16
      float v = s1n + s2[dl] + b;            // gathered 4B (L2-resident)
      v = v > 0.f ? v : LEAKY * v;
      h = __expf(v);
    }
    hs += h;
    const int cnt = min(64, r1 - base);
    const int pairs = (cnt + 1) >> 1;
    for (int t = 0; t < pairs; ++t) {
      const int sl = 2 * t + half;           // lanes beyond cnt carry h=0
      const float hB = __shfl(h, sl, 64);
      const int dB = __shfl(dl, sl, 64);
      const unsigned int w = *reinterpret_cast<const unsigned int*>(
          zb + (size_t)dB * HDIM + fp);
      const float z0 = __uint_as_float(w << 16);
      const float z1 = __uint_as_float(w & 0xffff0000u);
      ax = fmaf(hB, z0, ax);
      ay = fmaf(hB, z1, ay);
    }
  }
  #pragma unroll
  for (int off = 32; off > 0; off >>= 1) hs += __shfl_xor(hs, off, 64);
  // combine even/odd halves (same feature pair lives at lane^32)
  ax += __shfl_xor(ax, 32, 64);
  ay += __shfl_xor(ay, 32, 64);
  const float inv = 1.0f / hs;
  if (lane < 32) {
    float2 o = {ax * inv, ay * inv};
    *reinterpret_cast<float2*>(out + (size_t)node * HDIM + fp) = o;
    if (lane == 0) rinv[node] = inv;
  }
}

// ---------------------------------------------------------------------------
// K6: alpha in edge order (coalesced writes)
// ---------------------------------------------------------------------------
__global__ __launch_bounds__(256) void k_alpha(
    const int* __restrict__ src, const int* __restrict__ dst,
    const float* __restrict__ s1, const float* __restrict__ s2,
    const float* __restrict__ ab, const float* __restrict__ rinv,
    float* __restrict__ alpha, int E)
{
  int e = blockIdx.x * blockDim.x + threadIdx.x;
  if (e >= E) return;
  const int s = src[e];
  float v = s1[s] + s2[dst[e]] + ab[0];
  v = v > 0.f ? v : LEAKY * v;
  alpha[e] = __expf(v) * rinv[s];
}

extern "C" void kernel_launch(void* const* d_in, const int* in_sizes, int n_in,
                              void* d_out, int out_size, void* d_ws, size_t ws_size,
                              hipStream_t stream) {
  const int E  = in_sizes[1] / 2;
  const int H2 = in_sizes[3];            // 2*H = 128
  const int Hh = H2 / 2;                 // 64
  const int Ff = in_sizes[2] / Hh;       // 256
  const int N  = in_sizes[0] / Ff;       // 50000

  const float* x   = (const float*)d_in[0];
  const int*   ei  = (const int*)d_in[1];
  const float* fcw = (const float*)d_in[2];
  const float* aw  = (const float*)d_in[3];
  const float* ab  = (const float*)d_in[4];
  const int* src = ei;
  const int* dst = ei + E;

  float* out   = (float*)d_out;
  float* alpha = out + (size_t)N * HDIM;

  // workspace layout:
  // zb u16[N*64] | s1 f32[N] | s2 f32[N] | rinv f32[N] | wb s16[16384]
  // | cnt i32[N] | rowptr i32[N+1] | bsum i32[1024] | rank u16[E] | csr_dst u16[E]
  unsigned short* zb = (unsigned short*)d_ws;
  float* s1   = (float*)(zb + (size_t)N * HDIM);
  float* s2   = s1 + N;
  float* rinv = s2 + N;
  short* wb   = (short*)(rinv + N);
  int* cnt    = (int*)(wb + 8 * 4 * 64 * 8);
  int* rowptr = cnt + N;
  int* bsum   = rowptr + (N + 1);
  unsigned short* rank    = (unsigned short*)(bsum + 1024);
  unsigned short* csr_dst = rank + E;

  hipMemsetAsync(cnt, 0, (size_t)N * sizeof(int), stream);

  k_wt<<<8, 256, 0, stream>>>(fcw, wb);
  k_fcm<<<(N + 127) / 128, 256, 0, stream>>>(x, wb, aw, zb, s1, s2, N);

  const int eb = (E + 255) / 256;
  k_hist<<<eb, 256, 0, stream>>>(src, cnt, rank, E);

  const int nb1 = (N + 1023) / 1024;
  k_scan1<<<nb1, 1024, 0, stream>>>(cnt, rowptr, bsum, N);
  k_scan2<<<1, 1024, 0, stream>>>(bsum, nb1);
  k_scan3<<<nb1, 1024, 0, stream>>>(rowptr, bsum, N, E);

  k_place<<<eb, 256, 0, stream>>>(src, dst, rowptr, rank, csr_dst, E);

  k_node<<<(N + 3) / 4, 256, 0, stream>>>(
      csr_dst, rowptr, s1, s2, ab, zb, out, rinv, N);

  k_alpha<<<eb, 256, 0, stream>>>(src, dst, s1, s2, ab, rinv, alpha, E);
}

// Round 7
// 167.177 us; speedup vs baseline: 3.3210x; 1.2176x over previous
//
#include <hip/hip_runtime.h>
#include <hip/hip_bf16.h>
#include <cstdint>
#include <cstddef>

// GAT layer forward for MI355X (gfx950).
// N=50000, E=1.6M, F=256, H=64 (derived at runtime).
// Outputs (concat in d_out): out [N,H] f32, alpha [E] f32.

constexpr int FDIM = 256;
constexpr int HDIM = 64;
constexpr float LEAKY = 0.05f;
constexpr int CHUNK_LG = 15;              // 32768 edges per histogram block
constexpr int LH_CAP = 25088;             // u32 capacity: supports N <= 50176

typedef __attribute__((ext_vector_type(8))) short short8v;   // 8 bf16 = 4 VGPR
typedef __attribute__((ext_vector_type(4))) float f32x4;

__device__ __forceinline__ short bfs(float f) {
  return (short)__builtin_bit_cast(unsigned short, __float2bfloat16(f));
}
__device__ __forceinline__ short8v cvt8(float4 lo, float4 hi) {
  short8v r;
  r[0] = bfs(lo.x); r[1] = bfs(lo.y); r[2] = bfs(lo.z); r[3] = bfs(lo.w);
  r[4] = bfs(hi.x); r[5] = bfs(hi.y); r[6] = bfs(hi.z); r[7] = bfs(hi.w);
  return r;
}

// ---------------------------------------------------------------------------
// K0: pack fc_w (f32 [64][256]) into bf16 MFMA B-fragments.
// ---------------------------------------------------------------------------
__global__ __launch_bounds__(256) void k_wt(
    const float* __restrict__ fcw, short* __restrict__ wb)
{
  const int t = blockIdx.x * 256 + threadIdx.x;   // 0 .. 2047
  const int f = t >> 6;
  const int lane = t & 63;
  const int ks = f >> 2, cb = f & 3;
  const int col = cb * 16 + (lane & 15);
  const int kb = ks * 32 + (lane >> 4) * 8;
  short8v v;
  #pragma unroll
  for (int j = 0; j < 8; ++j) v[j] = bfs(fcw[col * FDIM + kb + j]);
  reinterpret_cast<short8v*>(wb)[t] = v;
}

// ---------------------------------------------------------------------------
// K1: MFMA GEMM z = x @ fc_w^T (bf16 in, f32 acc), fused s1/s2, z out bf16.
// C/D layout (verified): col = lane&15, row = (lane>>4)*4 + reg.
// ---------------------------------------------------------------------------
__global__ __launch_bounds__(256) void k_fcm(
    const float* __restrict__ x, const short* __restrict__ wb,
    const float* __restrict__ aw,
    unsigned short* __restrict__ zb, float* __restrict__ s1,
    float* __restrict__ s2, int N)
{
  __shared__ __align__(16) unsigned short zt[128 * 72];   // 18.4 KB transpose buf

  const int tid = threadIdx.x;
  const int lane = tid & 63;
  const int wave = tid >> 6;
  const int n0 = blockIdx.x * 128;
  const int rb = n0 + wave * 32;
  const int l4 = lane >> 4;      // k-group / row-group
  const int lm = lane & 15;      // A-row / B-col within tile

  f32x4 acc[2][4] = {};

  const int r0c = min(rb + lm, N - 1);
  const int r1c = min(rb + 16 + lm, N - 1);
  const float* xp0 = x + (size_t)r0c * FDIM + l4 * 8;
  const float* xp1 = x + (size_t)r1c * FDIM + l4 * 8;
  const short8v* wbv = reinterpret_cast<const short8v*>(wb);

  #pragma unroll
  for (int ks = 0; ks < 8; ++ks) {
    const float4 a0l = *reinterpret_cast<const float4*>(xp0 + ks * 32);
    const float4 a0h = *reinterpret_cast<const float4*>(xp0 + ks * 32 + 4);
    const float4 a1l = *reinterpret_cast<const float4*>(xp1 + ks * 32);
    const float4 a1h = *reinterpret_cast<const float4*>(xp1 + ks * 32 + 4);
    const short8v fa0 = cvt8(a0l, a0h);
    const short8v fa1 = cvt8(a1l, a1h);
    #pragma unroll
    for (int cb = 0; cb < 4; ++cb) {
      const short8v fb = wbv[(ks * 4 + cb) * 64 + lane];
      acc[0][cb] = __builtin_amdgcn_mfma_f32_16x16x32_bf16(fa0, fb, acc[0][cb], 0, 0, 0);
      acc[1][cb] = __builtin_amdgcn_mfma_f32_16x16x32_bf16(fa1, fb, acc[1][cb], 0, 0, 0);
    }
  }

  // fused s1/s2
  float aw1l[4], aw2l[4];
  #pragma unroll
  for (int cb = 0; cb < 4; ++cb) {
    aw1l[cb] = aw[cb * 16 + lm];
    aw2l[cb] = aw[HDIM + cb * 16 + lm];
  }
  #pragma unroll
  for (int mb = 0; mb < 2; ++mb) {
    const int rloc = rb + mb * 16 + l4 * 4;
    #pragma unroll
    for (int reg = 0; reg < 4; ++reg) {
      float t1 = 0.f, t2 = 0.f;
      #pragma unroll
      for (int cb = 0; cb < 4; ++cb) {
        t1 = fmaf(acc[mb][cb][reg], aw1l[cb], t1);
        t2 = fmaf(acc[mb][cb][reg], aw2l[cb], t2);
      }
      #pragma unroll
      for (int off = 1; off < 16; off <<= 1) {
        t1 += __shfl_xor(t1, off, 64);
        t2 += __shfl_xor(t2, off, 64);
      }
      if (lm == reg && rloc + reg < N) {
        s1[rloc + reg] = t1;
        s2[rloc + reg] = t2;
      }
    }
  }

  // z -> bf16 via LDS transpose, then coalesced stores (64B per thread)
  #pragma unroll
  for (int mb = 0; mb < 2; ++mb)
    #pragma unroll
    for (int cb = 0; cb < 4; ++cb)
      #pragma unroll
      for (int reg = 0; reg < 4; ++reg) {
        const int rl = wave * 32 + mb * 16 + l4 * 4 + reg;
        zt[rl * 72 + cb * 16 + lm] =
            (unsigned short)__builtin_bit_cast(unsigned short,
                __float2bfloat16(acc[mb][cb][reg]));
      }
  __syncthreads();
  const int row = tid >> 1, hf = tid & 1;   // 32 u16 = 64 B = 4 x uint4 each
  const int n = n0 + row;
  if (n < N) {
    const uint4* s = reinterpret_cast<const uint4*>(&zt[row * 72 + hf * 32]);
    uint4 v0 = s[0], v1 = s[1], v2 = s[2], v3 = s[3];
    uint4* d = reinterpret_cast<uint4*>(zb + (size_t)n * HDIM + hf * 32);
    d[0] = v0; d[1] = v1; d[2] = v2; d[3] = v3;
  }
}

// ---------------------------------------------------------------------------
// K2: LDS-privatized histogram. One block per 32768-edge chunk.
// Counts packed 2 x u16 per u32 (safe: per-node degree << 65536).
// Emits per-edge within-block rank (lrank) + per-block histogram row.
// ---------------------------------------------------------------------------
__global__ __launch_bounds__(1024) void k_histL(
    const int* __restrict__ src, unsigned int* __restrict__ hist,
    unsigned short* __restrict__ lrank, int E, int nCol)
{
  __shared__ unsigned int lh[LH_CAP];     // 100 KB
  const int tid = threadIdx.x;
  for (int i = tid; i < nCol; i += 1024) lh[i] = 0;
  __syncthreads();
  const int e0 = blockIdx.x << CHUNK_LG;
  const int e1 = min(e0 + (1 << CHUNK_LG), E);
  for (int e = e0 + tid; e < e1; e += 1024) {
    const int s = src[e];
    const int sh = (s & 1) * 16;
    const unsigned int old = atomicAdd(&lh[s >> 1], 1u << sh);
    lrank[e] = (unsigned short)((old >> sh) & 0xffffu);
  }
  __syncthreads();
  unsigned int* hrow = hist + (size_t)blockIdx.x * nCol;
  for (int i = tid; i < nCol; i += 1024) hrow[i] = lh[i];
}

// ---------------------------------------------------------------------------
// K2b: column scan over blocks (in-place: hist row b becomes exclusive base
// for block b), plus total counts cnt[n].
// ---------------------------------------------------------------------------
__global__ __launch_bounds__(256) void k_colscan(
    unsigned int* __restrict__ hist, int* __restrict__ cnt,
    int nCol, int B, int N)
{
  const int c = blockIdx.x * 256 + threadIdx.x;
  if (c >= nCol) return;
  unsigned int s0 = 0, s1 = 0;
  for (int b = 0; b < B; ++b) {
    unsigned int* p = hist + (size_t)b * nCol + c;
    const unsigned int v = *p;
    *p = s0 | (s1 << 16);
    s0 += v & 0xffffu;
    s1 += v >> 16;
  }
  const int n0 = 2 * c;
  if (n0 < N) cnt[n0] = (int)s0;
  if (n0 + 1 < N) cnt[n0 + 1] = (int)s1;
}

// ---------------------------------------------------------------------------
// K3a: per-block exclusive scan (1024/block) + block sums
// ---------------------------------------------------------------------------
__global__ __launch_bounds__(1024) void k_scan1(
    const int* __restrict__ cnt, int* __restrict__ rowptr,
    int* __restrict__ bsum, int N)
{
  __shared__ int wsum[16];
  const int i = blockIdx.x * 1024 + threadIdx.x;
  const int lane = threadIdx.x & 63;
  const int wave = threadIdx.x >> 6;
  const int v = (i < N) ? cnt[i] : 0;
  int s = v;
  #pragma unroll
  for (int off = 1; off < 64; off <<= 1) {
    int t = __shfl_up(s, off, 64);
    if (lane >= off) s += t;
  }
  if (lane == 63) wsum[wave] = s;
  __syncthreads();
  if (threadIdx.x < 16) {
    int w = wsum[threadIdx.x];
    #pragma unroll
    for (int off = 1; off < 16; off <<= 1) {
      int t = __shfl_up(w, off, 64);
      if (threadIdx.x >= off) w += t;
    }
    wsum[threadIdx.x] = w;   // inclusive across waves
  }
  __syncthreads();
  const int base = (wave > 0) ? wsum[wave - 1] : 0;
  if (i < N) rowptr[i] = base + s - v;      // block-local exclusive
  if (threadIdx.x == 0) bsum[blockIdx.x] = wsum[15];
}

// ---------------------------------------------------------------------------
// K3b: single-block exclusive scan of block sums (B <= 1024)
// ---------------------------------------------------------------------------
__global__ __launch_bounds__(1024) void k_scan2(int* __restrict__ bsum, int B)
{
  __shared__ int part[1024];
  const int t = threadIdx.x;
  const int v = (t < B) ? bsum[t] : 0;
  part[t] = v;
  __syncthreads();
  for (int off = 1; off < 1024; off <<= 1) {
    int u = (t >= off) ? part[t - off] : 0;
    __syncthreads();
    part[t] += u;
    __syncthreads();
  }
  if (t < B) bsum[t] = part[t] - v;   // exclusive
}

// ---------------------------------------------------------------------------
// K3c: add block offsets; set rowptr[N] = E
// ---------------------------------------------------------------------------
__global__ __launch_bounds__(1024) void k_scan3(
    int* __restrict__ rowptr, const int* __restrict__ bsum, int N, int E)
{
  const int i = blockIdx.x * 1024 + threadIdx.x;
  if (i < N) rowptr[i] += bsum[blockIdx.x];
  if (i == 0) rowptr[N] = E;
}

// ---------------------------------------------------------------------------
// K4: atomic-free CSR placement:
// pos = rowptr[src] + colbase[e>>15][src] + lrank[e]
// colbase row index (e>>15) is wave-uniform; both gather tables L2-resident.
// ---------------------------------------------------------------------------
__global__ __launch_bounds__(256) void k_place(
    const int* __restrict__ src, const int* __restrict__ dst,
    const int* __restrict__ rowptr, const unsigned int* __restrict__ colbase,
    const unsigned short* __restrict__ lrank,
    unsigned short* __restrict__ csr_dst, int E, int nCol)
{
  int e = blockIdx.x * 256 + threadIdx.x;
  if (e >= E) return;
  const int s = src[e];
  const unsigned int cb = colbase[(size_t)(e >> CHUNK_LG) * nCol + (s >> 1)];
  const int base = (int)((cb >> ((s & 1) * 16)) & 0xffffu);
  csr_dst[rowptr[s] + base + (int)lrank[e]] = (unsigned short)dst[e];
}

// ---------------------------------------------------------------------------
// K5: node-centric accumulate; wave/node; 2 edges per iteration.
// ---------------------------------------------------------------------------
__global__ __launch_bounds__(256) void k_node(
    const unsigned short* __restrict__ csr_dst, const int* __restrict__ rowptr,
    const float* __restrict__ s1, const float* __restrict__ s2,
    const float* __restrict__ ab, const unsigned short* __restrict__ zb,
    float* __restrict__ out, float* __restrict__ rinv, int N)
{
  const int node = blockIdx.x * 4 + (threadIdx.x >> 6);
  const int lane = threadIdx.x & 63;
  if (node >= N) return;
  const int r0 = rowptr[node];
  const int r1 = rowptr[node + 1];
  if (r1 == r0) {            // degree-0: reference yields zeros
    out[(size_t)node * HDIM + lane] = 0.f;
    if (lane == 0) rinv[node] = 0.f;
    return;
  }
  const float s1n = s1[node];
  const float b = ab[0];
  const int half = lane >> 5;
  const int fp = (lane & 31) << 1;   // feature pair base
  float ax = 0.f, ay = 0.f, hs = 0.f;

  for (int base = r0; base < r1; base += 64) {
    const int j = base + lane;
    float h = 0.f;
    int dl = 0;
    if (j < r1) {
      dl = (int)csr_dst[j];                  // coalesced u16
      float v = s1n + s2[dl] + b;            // gathered 4B (L2-resident)
      v = v > 0.f ? v : LEAKY * v;
      h = __expf(v);
    }
    hs += h;
    const int cnt = min(64, r1 - base);
    const int pairs = (cnt + 1) >> 1;
    #pragma unroll 4
    for (int t = 0; t < pairs; ++t) {
      const int sl = 2 * t + half;           // lanes beyond cnt carry h=0
      const float hB = __shfl(h, sl, 64);
      const int dB = __shfl(dl, sl, 64);
      const unsigned int w = *reinterpret_cast<const unsigned int*>(
          zb + (size_t)dB * HDIM + fp);
      const float z0 = __uint_as_float(w << 16);
      const float z1 = __uint_as_float(w & 0xffff0000u);
      ax = fmaf(hB, z0, ax);
      ay = fmaf(hB, z1, ay);
    }
  }
  #pragma unroll
  for (int off = 32; off > 0; off >>= 1) hs += __shfl_xor(hs, off, 64);
  // combine even/odd halves (same feature pair lives at lane^32)
  ax += __shfl_xor(ax, 32, 64);
  ay += __shfl_xor(ay, 32, 64);
  const float inv = 1.0f / hs;
  if (lane < 32) {
    float2 o = {ax * inv, ay * inv};
    *reinterpret_cast<float2*>(out + (size_t)node * HDIM + fp) = o;
    if (lane == 0) rinv[node] = inv;
  }
}

// ---------------------------------------------------------------------------
// K6: alpha in edge order (coalesced writes)
// ---------------------------------------------------------------------------
__global__ __launch_bounds__(256) void k_alpha(
    const int* __restrict__ src, const int* __restrict__ dst,
    const float* __restrict__ s1, const float* __restrict__ s2,
    const float* __restrict__ ab, const float* __restrict__ rinv,
    float* __restrict__ alpha, int E)
{
  int e = blockIdx.x * blockDim.x + threadIdx.x;
  if (e >= E) return;
  const int s = src[e];
  float v = s1[s] + s2[dst[e]] + ab[0];
  v = v > 0.f ? v : LEAKY * v;
  alpha[e] = __expf(v) * rinv[s];
}

extern "C" void kernel_launch(void* const* d_in, const int* in_sizes, int n_in,
                              void* d_out, int out_size, void* d_ws, size_t ws_size,
                              hipStream_t stream) {
  const int E  = in_sizes[1] / 2;
  const int H2 = in_sizes[3];            // 2*H = 128
  const int Hh = H2 / 2;                 // 64
  const int Ff = in_sizes[2] / Hh;       // 256
  const int N  = in_sizes[0] / Ff;       // 50000

  const float* x   = (const float*)d_in[0];
  const int*   ei  = (const int*)d_in[1];
  const float* fcw = (const float*)d_in[2];
  const float* aw  = (const float*)d_in[3];
  const float* ab  = (const float*)d_in[4];
  const int* src = ei;
  const int* dst = ei + E;

  float* out   = (float*)d_out;
  float* alpha = out + (size_t)N * HDIM;

  const int nCol = (N + 1) / 2;                       // packed u16-pair columns
  const int nbH  = (E + (1 << CHUNK_LG) - 1) >> CHUNK_LG;   // histogram blocks

  // workspace layout:
  // zb u16[N*64] | s1 f32[N] | s2 f32[N] | rinv f32[N] | wb s16[16384]
  // | cnt i32[N] | rowptr i32[N+1] | bsum i32[1024] | lrank u16[E]
  // | csr_dst u16[E] | hist u32[nbH*nCol]
  unsigned short* zb = (unsigned short*)d_ws;
  float* s1   = (float*)(zb + (size_t)N * HDIM);
  float* s2   = s1 + N;
  float* rinv = s2 + N;
  short* wb   = (short*)(rinv + N);
  int* cnt    = (int*)(wb + 8 * 4 * 64 * 8);
  int* rowptr = cnt + N;
  int* bsum   = rowptr + (N + 1);
  unsigned short* lrank   = (unsigned short*)(bsum + 1024);
  unsigned short* csr_dst = lrank + E;
  unsigned int* hist = (unsigned int*)(csr_dst + ((E + 1) & ~1));

  k_wt<<<8, 256, 0, stream>>>(fcw, wb);
  k_fcm<<<(N + 127) / 128, 256, 0, stream>>>(x, wb, aw, zb, s1, s2, N);

  k_histL<<<nbH, 1024, 0, stream>>>(src, hist, lrank, E, nCol);
  k_colscan<<<(nCol + 255) / 256, 256, 0, stream>>>(hist, cnt, nCol, nbH, N);

  const int nb1 = (N + 1023) / 1024;
  k_scan1<<<nb1, 1024, 0, stream>>>(cnt, rowptr, bsum, N);
  k_scan2<<<1, 1024, 0, stream>>>(bsum, nb1);
  k_scan3<<<nb1, 1024, 0, stream>>>(rowptr, bsum, N, E);

  const int eb = (E + 255) / 256;
  k_place<<<eb, 256, 0, stream>>>(src, dst, rowptr, hist, lrank, csr_dst, E, nCol);

  k_node<<<(N + 3) / 4, 256, 0, stream>>>(
      csr_dst, rowptr, s1, s2, ab, zb, out, rinv, N);

  k_alpha<<<eb, 256, 0, stream>>>(src, dst, s1, s2, ab, rinv, alpha, E);
}